// Round 13
// baseline (133.511 us; speedup 1.0000x reference)
//
#include <hip/hip_runtime.h>
#include <hip/hip_fp16.h>
#include <hip/hip_cooperative_groups.h>

namespace cg = cooperative_groups;

// N=4096, M=128, R=16, W=64, NG=1024, delta = 1/128 exactly.
// out[n,r,w] = sum_m red[n,r,m] * poly5(x0; coeff[idx,:,w])
// Approx: degree-1 + x0 sub-binned to 4 centers per cell:
//   tbl2[ii][w] = f16(c4[ii>>2][w]*(2*(ii&3)+1)/1024 + c5[ii>>2][w]), ii=(int)(x*512)
// This round: ONE cooperative kernel — phase 1 builds tbl2 (128 blocks' worth of
// threads), grid.sync, phase 2 = proven r11 body, 4 n per block, 1024 blocks
// (4/CU co-resident: 20KB LDS, VGPR<=128).

constexpr int MM = 128;
constexpr int RR = 16;
constexpr int WW = 64;
constexpr int NG = 1024;
constexpr int NROW = NG * 4;     // 4096 sub-binned rows
constexpr int CBLOCKS = 1024;
constexpr int ITERS = 4;         // 4096 / CBLOCKS

using f32x4 = __attribute__((ext_vector_type(4))) float;
using f16x8 = __attribute__((ext_vector_type(8))) _Float16;

__device__ __forceinline__ unsigned pk_f16(float lo, float hi) {
    auto h = __builtin_amdgcn_cvt_pkrtz(lo, hi);      // v_cvt_pkrtz_f16_f32
    unsigned r; __builtin_memcpy(&r, &h, 4); return r;
}

__global__ __launch_bounds__(256, 4)
void fused_kernel(const float* __restrict__ x,
                  unsigned* __restrict__ tbl,
                  const float* __restrict__ poly,
                  const float* __restrict__ red,
                  float* __restrict__ out)
{
    // rows of 128 f16 = 16 uint4 blocks, block idx swizzled ^ (row&7) (bank-floor)
    __shared__ uint4 eT[WW][16];   // 16 KB
    __shared__ uint4 rA[RR][16];   //  4 KB  -> 20 KB

    const int t   = threadIdx.x;
    const int c16 = t & 15;
    const int mq  = t >> 4;        // owned m-block (8 m's)
    const int q   = mq & 3;        // lane>>4
    const int wt  = t >> 6;

    // ---------------- phase 1: build tbl2 ----------------
    {
        const int gt = blockIdx.x * 256 + t;          // first 32768 threads write
        if (gt < NROW * 8) {
            const int g2 = gt >> 3;                   // fine row
            const int wo = gt & 7;                    // w-octet
            const int g  = g2 >> 2;
            const int s  = g2 & 3;
            const float x0c = (float)(2 * s + 1) * (1.0f / 1024.0f);
            const float* p = poly + (size_t)g * 384 + wo * 8;
            const float4 c4a = *(const float4*)(p + 256);
            const float4 c4b = *(const float4*)(p + 260);
            const float4 c5a = *(const float4*)(p + 320);
            const float4 c5b = *(const float4*)(p + 324);
            uint4 v;
            v.x = pk_f16(fmaf(c4a.x, x0c, c5a.x), fmaf(c4a.y, x0c, c5a.y));
            v.y = pk_f16(fmaf(c4a.z, x0c, c5a.z), fmaf(c4a.w, x0c, c5a.w));
            v.z = pk_f16(fmaf(c4b.x, x0c, c5b.x), fmaf(c4b.y, x0c, c5b.y));
            v.w = pk_f16(fmaf(c4b.z, x0c, c5b.z), fmaf(c4b.w, x0c, c5b.w));
            *(uint4*)(tbl + (size_t)g2 * 32 + wo * 4) = v;
        }
        __threadfence();                              // device-scope release
    }
    cg::this_grid().sync();                           // all XCDs see tbl2

    // ---------------- phase 2: 4 n's, r11 body ----------------
    for (int it = 0; it < ITERS; ++it) {
        const size_t n = (size_t)blockIdx.x * ITERS + it;

        const float* xp = x + n * MM + mq * 8;
        const float4 xa = *(const float4*)xp;
        const float4 xb = *(const float4*)(xp + 4);
        const float4* rv = (const float4*)(red + n * (RR * MM));
        const float4 ra = rv[2 * t];
        const float4 rb = rv[2 * t + 1];

        const float xs[8] = {xa.x, xa.y, xa.z, xa.w, xb.x, xb.y, xb.z, xb.w};
        uint2 g[8];   // lane's 4 w's (w = c16*4..+3) for m = mq*8 + j
#pragma unroll
        for (int j = 0; j < 8; ++j) {
            const int ii = (int)(xs[j] * 512.0f);     // exact pow2; (ii>>2) == ref idx
            g[j] = *(const uint2*)(tbl + (size_t)ii * 32 + c16 * 2);
        }

        // rA stage (thread holds red row mq, cols c16*8..+7)
        {
            uint4 rp;
            rp.x = pk_f16(ra.x, ra.y); rp.y = pk_f16(ra.z, ra.w);
            rp.z = pk_f16(rb.x, rb.y); rp.w = pk_f16(rb.z, rb.w);
            rA[mq][c16 ^ (mq & 7)] = rp;
        }

        // eT stage: v_perm repack (m-pair per u32), zero arithmetic
#pragma unroll
        for (int c = 0; c < 4; ++c) {
            const int w   = c16 * 4 + c;
            const unsigned sel = (c & 1) ? 0x07060302u : 0x05040100u;
            unsigned e[4];
#pragma unroll
            for (int pp = 0; pp < 4; ++pp) {
                const unsigned gl = (c >> 1) ? g[2 * pp].y     : g[2 * pp].x;
                const unsigned gh = (c >> 1) ? g[2 * pp + 1].y : g[2 * pp + 1].x;
                e[pp] = __builtin_amdgcn_perm(gh, gl, sel);   // (e[2p+1,w]<<16)|e[2p,w]
            }
            uint4 v; v.x = e[0]; v.y = e[1]; v.z = e[2]; v.w = e[3];
            eT[w][mq ^ (w & 7)] = v;
        }

        __syncthreads();

        // MFMA: wave wt -> out[n][0:16][wt*16..+16], K=128 as 4x 16x16x32
        const int sa   = c16 & 7;
        const int rowb = wt * 16 + c16;               // rowb&7 == sa
        f32x4 acc = {0.f, 0.f, 0.f, 0.f};
#pragma unroll
        for (int kc = 0; kc < 4; ++kc) {
            const int bk = kc * 4 + q;
            const uint4 av = rA[c16][bk ^ sa];
            const uint4 bv = eT[rowb][bk ^ sa];
            f16x8 af, bf;
            __builtin_memcpy(&af, &av, 16);
            __builtin_memcpy(&bf, &bv, 16);
            acc = __builtin_amdgcn_mfma_f32_16x16x32_f16(af, bf, acc, 0, 0, 0);
        }

        // C/D layout: col = lane&15 (w), row = (lane>>4)*4 + reg (r)
        float* op = out + n * (RR * WW) + (size_t)(q * 4) * WW + rowb;
        op[0 * WW] = acc[0];
        op[1 * WW] = acc[1];
        op[2 * WW] = acc[2];
        op[3 * WW] = acc[3];

        if (it + 1 < ITERS) __syncthreads();          // WAR before restage
    }
}

// ---- fallback (no workspace): direct poly gather, non-cooperative ----
__global__ __launch_bounds__(256, 4)
void embed_fallback_kernel(const float* __restrict__ x,
                           const float* __restrict__ poly,
                           const float* __restrict__ red,
                           float* __restrict__ out)
{
    __shared__ uint4 eT[WW][16];
    __shared__ uint4 rA[RR][16];

    const int n   = blockIdx.x;
    const int t   = threadIdx.x;
    const int c16 = t & 15;
    const int mq  = t >> 4;
    const int q   = mq & 3;
    const int wt  = t >> 6;

    const float* xp = x + (size_t)n * MM + mq * 8;
    const float4 xa = *(const float4*)xp;
    const float4 xb = *(const float4*)(xp + 4);
    const float4* rv = (const float4*)(red + (size_t)n * (RR * MM));
    const float4 ra = rv[2 * t];
    const float4 rb = rv[2 * t + 1];

    const float xs[8] = {xa.x, xa.y, xa.z, xa.w, xb.x, xb.y, xb.z, xb.w};
    uint2 g[8];
#pragma unroll
    for (int j = 0; j < 8; ++j) {
        const int ii = (int)(xs[j] * 512.0f);
        const int ic = ii >> 2;
        const float x0 = xs[j] - (float)ic * 0.0078125f;
        const float* pc = poly + (size_t)ic * 384 + c16 * 4;
        const float4 c4 = *(const float4*)(pc + 256);
        const float4 c5 = *(const float4*)(pc + 320);
        g[j].x = pk_f16(fmaf(c4.x, x0, c5.x), fmaf(c4.y, x0, c5.y));
        g[j].y = pk_f16(fmaf(c4.z, x0, c5.z), fmaf(c4.w, x0, c5.w));
    }
    {
        uint4 rp;
        rp.x = pk_f16(ra.x, ra.y); rp.y = pk_f16(ra.z, ra.w);
        rp.z = pk_f16(rb.x, rb.y); rp.w = pk_f16(rb.z, rb.w);
        rA[mq][c16 ^ (mq & 7)] = rp;
    }
#pragma unroll
    for (int c = 0; c < 4; ++c) {
        const int w   = c16 * 4 + c;
        const unsigned sel = (c & 1) ? 0x07060302u : 0x05040100u;
        unsigned e[4];
#pragma unroll
        for (int pp = 0; pp < 4; ++pp) {
            const unsigned gl = (c >> 1) ? g[2 * pp].y     : g[2 * pp].x;
            const unsigned gh = (c >> 1) ? g[2 * pp + 1].y : g[2 * pp + 1].x;
            e[pp] = __builtin_amdgcn_perm(gh, gl, sel);
        }
        uint4 v; v.x = e[0]; v.y = e[1]; v.z = e[2]; v.w = e[3];
        eT[w][mq ^ (w & 7)] = v;
    }
    __syncthreads();
    const int sa   = c16 & 7;
    const int rowb = wt * 16 + c16;
    f32x4 acc = {0.f, 0.f, 0.f, 0.f};
#pragma unroll
    for (int kc = 0; kc < 4; ++kc) {
        const int bk = kc * 4 + q;
        const uint4 av = rA[c16][bk ^ sa];
        const uint4 bv = eT[rowb][bk ^ sa];
        f16x8 af, bf;
        __builtin_memcpy(&af, &av, 16);
        __builtin_memcpy(&bf, &bv, 16);
        acc = __builtin_amdgcn_mfma_f32_16x16x32_f16(af, bf, acc, 0, 0, 0);
    }
    float* op = out + (size_t)n * (RR * WW) + (size_t)(q * 4) * WW + rowb;
    op[0 * WW] = acc[0];
    op[1 * WW] = acc[1];
    op[2 * WW] = acc[2];
    op[3 * WW] = acc[3];
}

extern "C" void kernel_launch(void* const* d_in, const int* in_sizes, int n_in,
                              void* d_out, int out_size, void* d_ws, size_t ws_size,
                              hipStream_t stream) {
    const float* x    = (const float*)d_in[0];
    const float* poly = (const float*)d_in[1];
    const float* red  = (const float*)d_in[2];
    float* out = (float*)d_out;
    const int N = in_sizes[0] / MM;   // 4096

    if (ws_size >= (size_t)NROW * 32 * sizeof(unsigned) && N == CBLOCKS * ITERS) {
        unsigned* tbl = (unsigned*)d_ws;
        void* args[5];
        args[0] = (void*)&x;
        args[1] = (void*)&tbl;
        args[2] = (void*)&poly;
        args[3] = (void*)&red;
        args[4] = (void*)&out;
        hipLaunchCooperativeKernel((void*)fused_kernel, dim3(CBLOCKS), dim3(256),
                                   args, 0, stream);
    } else {
        embed_fallback_kernel<<<N, 256, 0, stream>>>(x, poly, red, out);
    }
}

// Round 14
// 21.285 us; speedup vs baseline: 6.2726x; 6.2726x over previous
//
#include <hip/hip_runtime.h>
#include <hip/hip_fp16.h>

// N=4096, M=128, R=16, W=64, NG=1024, delta = 1/128 exactly.
// out[n,r,w] = sum_m red[n,r,m] * poly5(x0; coeff[idx,:,w])
// Approx: degree-1 + x0 sub-binned to 4 centers per cell:
//   tbl2[ii][w] = f16(c4[ii>>2][w]*(2*(ii&3)+1)/1024 + c5[ii>>2][w]), ii=(int)(x*512)
// Main kernel: zero polynomial arithmetic; gathered u16s ARE the embed values.
// This round: REVERT to r11 (best: 21.29us) + exact byte-offset gather addressing
// (off = ((int)(x*65536)) & ~127 == floor(x*512)*128, saves a mul per gather).

constexpr int MM = 128;
constexpr int RR = 16;
constexpr int WW = 64;
constexpr int NG = 1024;
constexpr int NROW = NG * 4;   // 4096 sub-binned rows

using f32x4 = __attribute__((ext_vector_type(4))) float;
using f16x8 = __attribute__((ext_vector_type(8))) _Float16;

__device__ __forceinline__ unsigned pk_f16(float lo, float hi) {
    auto h = __builtin_amdgcn_cvt_pkrtz(lo, hi);      // v_cvt_pkrtz_f16_f32
    unsigned r; __builtin_memcpy(&r, &h, 4); return r;
}

// ---- prepass: tbl2 rows of 64 f16 (32 u32 words); uint4 per thread ----
__global__ __launch_bounds__(256)
void build_tbl2_kernel(const float* __restrict__ poly, unsigned* __restrict__ tbl) {
    const int t  = blockIdx.x * 256 + threadIdx.x;    // 32768
    const int g2 = t >> 3;          // fine row 0..4095
    const int wo = t & 7;           // w-octet: w = wo*8 .. +7
    const int g  = g2 >> 2;
    const int s  = g2 & 3;
    const float x0c = (float)(2 * s + 1) * (1.0f / 1024.0f);
    const float* p = poly + (size_t)g * 384 + wo * 8;
    const float4 c4a = *(const float4*)(p + 256);
    const float4 c4b = *(const float4*)(p + 260);
    const float4 c5a = *(const float4*)(p + 320);
    const float4 c5b = *(const float4*)(p + 324);
    uint4 v;
    v.x = pk_f16(fmaf(c4a.x, x0c, c5a.x), fmaf(c4a.y, x0c, c5a.y));
    v.y = pk_f16(fmaf(c4a.z, x0c, c5a.z), fmaf(c4a.w, x0c, c5a.w));
    v.z = pk_f16(fmaf(c4b.x, x0c, c5b.x), fmaf(c4b.y, x0c, c5b.y));
    v.w = pk_f16(fmaf(c4b.z, x0c, c5b.z), fmaf(c4b.w, x0c, c5b.w));
    *(uint4*)(tbl + (size_t)g2 * 32 + wo * 4) = v;
}

template<bool USE_TBL>
__global__ __launch_bounds__(256, 8)
void embed_mfma_kernel(const float* __restrict__ x,
                       const unsigned* __restrict__ tbl,
                       const float* __restrict__ poly,
                       const float* __restrict__ red,
                       float* __restrict__ out)
{
    // rows of 128 f16 = 16 uint4 blocks, block idx swizzled ^ (row&7)
    // (all 4 LDS access patterns verified at the b128 8-pass bank floor)
    __shared__ uint4 eT[WW][16];   // 16 KB
    __shared__ uint4 rA[RR][16];   //  4 KB  -> 20 KB total

    const int n   = blockIdx.x;
    const int t   = threadIdx.x;
    const int c16 = t & 15;
    const int mq  = t >> 4;        // 0..15: owned m-block (8 m's)
    const int q   = mq & 3;        // lane>>4
    const int wt  = t >> 6;

    // ---- x first (heads the serial chain x -> idx -> gather) ----
    const float* xp = x + (size_t)n * MM + mq * 8;
    const float4 xa = *(const float4*)xp;
    const float4 xb = *(const float4*)(xp + 4);
    // ---- red second (latency hides under gather issue/processing) ----
    const float4* rv = (const float4*)(red + (size_t)n * (RR * MM));
    const float4 ra = rv[2 * t];
    const float4 rb = rv[2 * t + 1];

    const float xs[8] = {xa.x, xa.y, xa.z, xa.w, xb.x, xb.y, xb.z, xb.w};

    uint2 g[8];   // lane's 4 w's (w = c16*4..+3) for m = mq*8 + j
    if (USE_TBL) {
        const char* tb = (const char*)tbl + c16 * 8;
        // 16-lane group shares row ii -> one 128B line per row, 4 rows per instr
#pragma unroll
        for (int j = 0; j < 8; ++j) {
            // exact: x*65536 is an exact pow2-scaled f32 product; &~127 == floor(x*512)*128
            const int off = ((int)(xs[j] * 65536.0f)) & 0xFFFFFF80;
            g[j] = *(const uint2*)(tb + off);
        }
    } else {
#pragma unroll
        for (int j = 0; j < 8; ++j) {
            const int ii = (int)(xs[j] * 512.0f);
            const int ic = ii >> 2;
            const float x0 = xs[j] - (float)ic * 0.0078125f;
            const float* pc = poly + (size_t)ic * 384 + c16 * 4;
            const float4 c4 = *(const float4*)(pc + 256);
            const float4 c5 = *(const float4*)(pc + 320);
            g[j].x = pk_f16(fmaf(c4.x, x0, c5.x), fmaf(c4.y, x0, c5.y));
            g[j].y = pk_f16(fmaf(c4.z, x0, c5.z), fmaf(c4.w, x0, c5.w));
        }
    }

    // ---- rA stage (thread holds red row mq, cols c16*8..+7) ----
    {
        uint4 rp;
        rp.x = pk_f16(ra.x, ra.y); rp.y = pk_f16(ra.z, ra.w);
        rp.z = pk_f16(rb.x, rb.y); rp.w = pk_f16(rb.z, rb.w);
        rA[mq][c16 ^ (mq & 7)] = rp;
    }

    // ---- eT stage: v_perm repack (m-pair per u32), zero arithmetic ----
#pragma unroll
    for (int c = 0; c < 4; ++c) {
        const int w   = c16 * 4 + c;
        const unsigned sel = (c & 1) ? 0x07060302u : 0x05040100u;
        unsigned e[4];
#pragma unroll
        for (int p = 0; p < 4; ++p) {
            const unsigned gl = (c >> 1) ? g[2 * p].y     : g[2 * p].x;
            const unsigned gh = (c >> 1) ? g[2 * p + 1].y : g[2 * p + 1].x;
            e[p] = __builtin_amdgcn_perm(gh, gl, sel);   // (e[2p+1,w]<<16)|e[2p,w]
        }
        uint4 v; v.x = e[0]; v.y = e[1]; v.z = e[2]; v.w = e[3];
        eT[w][mq ^ (w & 7)] = v;
    }

    __syncthreads();

    // ---- MFMA: wave wt -> out[n][0:16][wt*16..+16], K=128 as 4x 16x16x32 ----
    const int sa   = c16 & 7;
    const int rowb = wt * 16 + c16;          // rowb&7 == sa
    f32x4 acc = {0.f, 0.f, 0.f, 0.f};
#pragma unroll
    for (int kc = 0; kc < 4; ++kc) {
        const int bk = kc * 4 + q;
        const uint4 av = rA[c16][bk ^ sa];
        const uint4 bv = eT[rowb][bk ^ sa];
        f16x8 af, bf;
        __builtin_memcpy(&af, &av, 16);
        __builtin_memcpy(&bf, &bv, 16);
        acc = __builtin_amdgcn_mfma_f32_16x16x32_f16(af, bf, acc, 0, 0, 0);
    }

    // C/D layout: col = lane&15 (w), row = (lane>>4)*4 + reg (r)
    float* op = out + (size_t)n * (RR * WW) + (size_t)(q * 4) * WW + rowb;
    op[0 * WW] = acc[0];
    op[1 * WW] = acc[1];
    op[2 * WW] = acc[2];
    op[3 * WW] = acc[3];
}

extern "C" void kernel_launch(void* const* d_in, const int* in_sizes, int n_in,
                              void* d_out, int out_size, void* d_ws, size_t ws_size,
                              hipStream_t stream) {
    const float* x    = (const float*)d_in[0];
    const float* poly = (const float*)d_in[1];
    const float* red  = (const float*)d_in[2];
    float* out = (float*)d_out;
    const int N = in_sizes[0] / MM;   // 4096

    if (ws_size >= (size_t)NROW * 32 * sizeof(unsigned)) {
        unsigned* tbl = (unsigned*)d_ws;
        build_tbl2_kernel<<<(NROW * 8) / 256, 256, 0, stream>>>(poly, tbl);
        embed_mfma_kernel<true><<<N, 256, 0, stream>>>(x, tbl, poly, red, out);
    } else {
        embed_mfma_kernel<false><<<N, 256, 0, stream>>>(x, nullptr, poly, red, out);
    }
}